// Round 6
// baseline (10379.564 us; speedup 1.0000x reference)
//
#include <hip/hip_runtime.h>

#define TT 1024
#define BB 32
#define HH 512

typedef __attribute__((ext_vector_type(8))) __bf16 bf16x8;
typedef __attribute__((ext_vector_type(8))) short short8;
typedef __attribute__((ext_vector_type(4))) float f32x4;

union frag_u {
  short8 s;
  bf16x8 b;
  f32x4 f;
  unsigned long long q[2];
  unsigned int d[4];
};

__device__ __forceinline__ unsigned short f2bf(float f) {
  unsigned int u = __float_as_uint(f);
  u += 0x7FFFu + ((u >> 16) & 1u);
  return (unsigned short)(u >> 16);
}

__device__ __forceinline__ bf16x8 cvt8(const float* p) {
  frag_u u;
#pragma unroll
  for (int j = 0; j < 8; ++j) u.s[j] = (short)f2bf(p[j]);
  return u.b;
}

__device__ __forceinline__ float sigm(float x) {
  return __builtin_amdgcn_rcpf(1.0f + __expf(-x));
}
__device__ __forceinline__ float tanh_(float x) {
  return 1.0f - 2.0f * __builtin_amdgcn_rcpf(1.0f + __expf(2.0f * x));
}

__device__ __forceinline__ void lgkm0() {
  asm volatile("s_waitcnt lgkmcnt(0)" ::: "memory");
}

// Issue 16 coherence-point (sc0 sc1) 16B loads of one h fragment in the
// slice-blocked layout. fr[kc] = MFMA A-operand for K-block kc directly.
// NO WAIT inside: pair with POLLWAIT. Speculative issue is safe because
// every fragment is sentinel-validated before use.
#define GISSUE16(A0, A1, A2, A3, FR)                                        \
  asm volatile(                                                             \
      "global_load_dwordx4 %0, %16, off sc0 sc1\n\t"                        \
      "global_load_dwordx4 %1, %16, off offset:1024 sc0 sc1\n\t"            \
      "global_load_dwordx4 %2, %16, off offset:2048 sc0 sc1\n\t"            \
      "global_load_dwordx4 %3, %16, off offset:3072 sc0 sc1\n\t"            \
      "global_load_dwordx4 %4, %17, off sc0 sc1\n\t"                        \
      "global_load_dwordx4 %5, %17, off offset:1024 sc0 sc1\n\t"            \
      "global_load_dwordx4 %6, %17, off offset:2048 sc0 sc1\n\t"            \
      "global_load_dwordx4 %7, %17, off offset:3072 sc0 sc1\n\t"            \
      "global_load_dwordx4 %8, %18, off sc0 sc1\n\t"                        \
      "global_load_dwordx4 %9, %18, off offset:1024 sc0 sc1\n\t"            \
      "global_load_dwordx4 %10, %18, off offset:2048 sc0 sc1\n\t"           \
      "global_load_dwordx4 %11, %18, off offset:3072 sc0 sc1\n\t"           \
      "global_load_dwordx4 %12, %19, off sc0 sc1\n\t"                       \
      "global_load_dwordx4 %13, %19, off offset:1024 sc0 sc1\n\t"           \
      "global_load_dwordx4 %14, %19, off offset:2048 sc0 sc1\n\t"           \
      "global_load_dwordx4 %15, %19, off offset:3072 sc0 sc1"               \
      : "=&v"((FR)[0].f), "=&v"((FR)[1].f), "=&v"((FR)[2].f),               \
        "=&v"((FR)[3].f), "=&v"((FR)[4].f), "=&v"((FR)[5].f),               \
        "=&v"((FR)[6].f), "=&v"((FR)[7].f), "=&v"((FR)[8].f),               \
        "=&v"((FR)[9].f), "=&v"((FR)[10].f), "=&v"((FR)[11].f),             \
        "=&v"((FR)[12].f), "=&v"((FR)[13].f), "=&v"((FR)[14].f),            \
        "=&v"((FR)[15].f)                                                   \
      : "v"((A0)), "v"((A1)), "v"((A2)), "v"((A3))                          \
      : "memory")

#define POLLWAIT                                       \
  do {                                                 \
    asm volatile("s_waitcnt vmcnt(0)" ::: "memory");   \
    __builtin_amdgcn_sched_barrier(0);                 \
  } while (0)

__device__ __forceinline__ unsigned int frbad(const frag_u fr[16]) {
  unsigned int bad = 0u;
#pragma unroll
  for (int j = 0; j < 16; ++j)
#pragma unroll
    for (int d = 0; d < 4; ++d) bad |= (fr[j].d[d] == 0xFFFFFFFFu) ? 1u : 0u;
  return bad;
}

// Poll loop with round-1 ALREADY ISSUED (speculatively, at prev iter end or
// prologue): wait -> check -> reissue.
#define POLLLOOP(FR, B0)                                                    \
  do {                                                                      \
    int it_ = 0;                                                            \
    for (;;) {                                                              \
      POLLWAIT;                                                             \
      if (__all(frbad(FR) == 0u)) break;                                    \
      if (++it_ > (1 << 20)) break;                                         \
      GISSUE16((B0), (B0) + 4096, (B0) + 8192, (B0) + 12288, FR);           \
    }                                                                       \
  } while (0)

__global__ void xcvt(const float* __restrict__ x, unsigned short* __restrict__ xbf) {
  size_t i = (size_t)blockIdx.x * blockDim.x + threadIdx.x;  // 8192*256 = n/8 exact
  const f32x4* p = (const f32x4*)x + 2 * i;
  f32x4 a = p[0], b = p[1];
  short8 o;
  o[0] = (short)f2bf(a[0]); o[1] = (short)f2bf(a[1]);
  o[2] = (short)f2bf(a[2]); o[3] = (short)f2bf(a[3]);
  o[4] = (short)f2bf(b[0]); o[5] = (short)f2bf(b[1]);
  o[6] = (short)f2bf(b[2]); o[7] = (short)f2bf(b[3]);
  *((short8*)xbf + i) = o;
}

// Poison both h buffers with the sentinel pattern via agent-scope stores.
// Per buffer: (TT+1)*32KB = 4,198,400 qwords = 4100 blocks * 1024.
__global__ void hfill(unsigned long long* __restrict__ a,
                      unsigned long long* __restrict__ b) {
  size_t base = (size_t)blockIdx.x * 1024 + threadIdx.x;
#pragma unroll
  for (int k = 0; k < 4; ++k) {
    size_t i = base + (size_t)k * 256;
    __hip_atomic_store(a + i, ~0ull, __ATOMIC_RELAXED, __HIP_MEMORY_SCOPE_AGENT);
    __hip_atomic_store(b + i, ~0ull, __ATOMIC_RELAXED, __HIP_MEMORY_SCOPE_AGENT);
  }
}

// h buffers: slice-blocked layout [t][mhalf][slice(64)][row(16)][col(8)] bf16.
// Publish = one 4B store/lane (4 full lines/wave). Consume = 16 x dwordx4,
// each lane-load IS an MFMA A-fragment.
//
// R6 pipelining: round-1 poll loads are issued SPECULATIVELY right after the
// publish (their RT overlaps peer visibility + out-stores + input loads);
// input-projection (xbf) loads for step t+1 are issued at the end of step t
// and consumed after the poll.
__global__ __launch_bounds__(64, 1) void lstm_persistent(
    const float* __restrict__ x,
    const float* __restrict__ wih0, const float* __restrict__ whh0,
    const float* __restrict__ bih0, const float* __restrict__ bhh0,
    const float* __restrict__ wih1, const float* __restrict__ whh1,
    const float* __restrict__ bih1, const float* __restrict__ bhh1,
    const float* __restrict__ h0in, const float* __restrict__ c0in,
    float* __restrict__ out,
    const unsigned short* __restrict__ xbf,  // may be null -> read x fp32 directly
    unsigned short* __restrict__ h0buf,      // slice-blocked, sentinel-poisoned
    unsigned short* __restrict__ h1buf)
{
  __shared__ unsigned int xlds[64];          // 256B transpose scratch (1 wave/block)

  const int lane = threadIdx.x;            // 0..63
  const int bid = blockIdx.x;              // 0..255
  const int layer = bid >> 7;
  const int sub = bid & 127;
  const int mhalf = sub & 1;               // batch half
  const int slice = sub >> 1;              // 0..63 -> 8 h-cols each
  const int hc0 = slice << 3;
  const int q = lane >> 4;                 // MFMA quad
  const int c16 = lane & 15;               // MFMA n / m index
  const int cmod = lane & 7;
  const bool owner = (c16 < 8);
  const bool pstore = owner && !(c16 & 1); // packed-pair publisher lanes
  const int mbase = mhalf << 4;

  const float* wih = layer ? wih1 : wih0;
  const float* whh = layer ? whh1 : whh0;
  const float* bih = layer ? bih1 : bih0;
  const float* bhh = layer ? bhh1 : bhh0;

  // gate-column map: acc0 -> {i, f}, acc1 -> {g, o} for h-cols hc0..hc0+7
  const int colN0 = owner ? (hc0 + c16) : (512 + hc0 + c16 - 8);
  const int colN1 = owner ? (1024 + hc0 + c16) : (1536 + hc0 + c16 - 8);

  // ---- persistent weight fragments: [W_ih | W_hh] bf16, 256 VGPRs ----
  bf16x8 w0[32], w1[32];
#pragma unroll
  for (int kc = 0; kc < 32; ++kc) {
    const float* s0;
    const float* s1;
    if (kc < 16) {
      s0 = wih + (size_t)colN0 * HH + kc * 32 + q * 8;
      s1 = wih + (size_t)colN1 * HH + kc * 32 + q * 8;
    } else {
      s0 = whh + (size_t)colN0 * HH + (kc - 16) * 32 + q * 8;
      s1 = whh + (size_t)colN1 * HH + (kc - 16) * 32 + q * 8;
    }
    w0[kc] = cvt8(s0);
    w1[kc] = cvt8(s1);
  }
  const float bias0 = bih[colN0] + bhh[colN0];
  const float bias1 = bih[colN1] + bhh[colN1];

  // ---- initial cell state (pair lanes keep duplicates) ----
  float creg[4];
#pragma unroll
  for (int r = 0; r < 4; ++r) {
    int batch = mbase + q * 4 + r;
    creg[r] = c0in[(size_t)layer * BB * HH + (size_t)batch * HH + hc0 + cmod];
  }

  unsigned short* myH = layer ? h1buf : h0buf;
  char* pubbase = (char*)myH + (size_t)mhalf * 16384 + (size_t)slice * 256 +
                  (size_t)lane * 4;

  const size_t laneoff = (size_t)(mbase + c16) * HH + q * 8;  // shorts (x rows)
  const size_t rdlane = (size_t)q * 256 + (size_t)c16 * 16;   // bytes in h layout

  // ---- publish h_0 slice via LDS transpose + one wide store ----
  {
    float hv0[4];
#pragma unroll
    for (int r = 0; r < 4; ++r) {
      int batch = mbase + q * 4 + r;
      hv0[r] = h0in[(size_t)layer * BB * HH + (size_t)batch * HH + hc0 + cmod];
    }
#pragma unroll
    for (int r = 0; r < 4; ++r) {
      unsigned short hb = f2bf(hv0[r]);
      unsigned int partner = (unsigned int)__shfl_xor((int)(unsigned int)hb, 1);
      unsigned int packed = ((unsigned int)hb & 0xffffu) | (partner << 16);
      if (pstore) xlds[(q * 4 + r) * 4 + (cmod >> 1)] = packed;
    }
    lgkm0();
    unsigned int v = xlds[lane];
    __hip_atomic_store((unsigned int*)pubbase, v, __ATOMIC_RELAXED,
                       __HIP_MEMORY_SCOPE_AGENT);
    asm volatile("" ::: "memory");
  }

  // Persistent poll/prefetch state.
  frag_u fr[16];   // L0: own h[t-1]    | L1: used as fb (own h1[t-1])
  frag_u fa[16];   // L1 only: h0[t]
  bf16x8 xa[16];   // L0 only: xbf[t] prefetch

  const bool use_xa = (layer == 0) && (xbf != nullptr);

  // ---- prologue speculative issues ----
  if (layer == 0) {
    const char* hb = (const char*)myH + (size_t)mhalf * 16384 + rdlane;  // h[0]
    GISSUE16(hb, hb + 4096, hb + 8192, hb + 12288, fr);
    if (use_xa) {
      const unsigned short* ip = xbf + laneoff;  // t = 1 input
#pragma unroll
      for (int kc = 0; kc < 16; ++kc)
        xa[kc] = *(const bf16x8*)(const void*)(ip + kc * 32);
    }
  } else {
    const char* hb = (const char*)h1buf + (size_t)mhalf * 16384 + rdlane;  // h1[0]
    GISSUE16(hb, hb + 4096, hb + 8192, hb + 12288, fr);
    const char* ha = (const char*)h0buf + ((size_t)2 + mhalf) * 16384 + rdlane;  // h0[1]
    GISSUE16(ha, ha + 4096, ha + 8192, ha + 12288, fa);
  }

  for (int t = 1; t <= TT; ++t) {
    f32x4 acc0 = {bias0, bias0, bias0, bias0};
    f32x4 acc1 = {bias1, bias1, bias1, bias1};

    if (layer == 0) {
      // ---- poll own h[t-1]; round-1 already in flight ----
      const char* hb = (const char*)myH +
                       ((size_t)(t - 1) * 2 + mhalf) * 16384 + rdlane;
      POLLLOOP(fr, hb);
      // rec MFMAs
#pragma unroll
      for (int kc = 0; kc < 16; ++kc) {
        acc0 = __builtin_amdgcn_mfma_f32_16x16x32_bf16(fr[kc].b, w0[16 + kc], acc0, 0, 0, 0);
        acc1 = __builtin_amdgcn_mfma_f32_16x16x32_bf16(fr[kc].b, w1[16 + kc], acc1, 0, 0, 0);
      }
      // input projection: xa prefetched last iter (drained by POLLWAIT)
      if (use_xa) {
#pragma unroll
        for (int kc = 0; kc < 16; ++kc) {
          acc0 = __builtin_amdgcn_mfma_f32_16x16x32_bf16(xa[kc], w0[kc], acc0, 0, 0, 0);
          acc1 = __builtin_amdgcn_mfma_f32_16x16x32_bf16(xa[kc], w1[kc], acc1, 0, 0, 0);
        }
      } else {
        const float* ip = x + (size_t)(t - 1) * BB * HH + laneoff;
#pragma unroll
        for (int kc = 0; kc < 16; ++kc) {
          bf16x8 a = cvt8(ip + kc * 32);
          acc0 = __builtin_amdgcn_mfma_f32_16x16x32_bf16(a, w0[kc], acc0, 0, 0, 0);
          acc1 = __builtin_amdgcn_mfma_f32_16x16x32_bf16(a, w1[kc], acc1, 0, 0, 0);
        }
      }
    } else {
      // ---- L1: poll own h1[t-1] (fb == fr); round-1 in flight ----
      const char* hb = (const char*)h1buf +
                       ((size_t)(t - 1) * 2 + mhalf) * 16384 + rdlane;
      POLLLOOP(fr, hb);
#pragma unroll
      for (int kc = 0; kc < 16; ++kc) {
        acc0 = __builtin_amdgcn_mfma_f32_16x16x32_bf16(fr[kc].b, w0[16 + kc], acc0, 0, 0, 0);
        acc1 = __builtin_amdgcn_mfma_f32_16x16x32_bf16(fr[kc].b, w1[16 + kc], acc1, 0, 0, 0);
      }
      // ---- h0[t]: round-1 issued long ago (prev iter end); usually valid ----
      const char* ha = (const char*)h0buf +
                       ((size_t)t * 2 + mhalf) * 16384 + rdlane;
      if (!__all(frbad(fa) == 0u)) {
        int it_ = 0;
        for (;;) {
          GISSUE16(ha, ha + 4096, ha + 8192, ha + 12288, fa);
          POLLWAIT;
          if (__all(frbad(fa) == 0u)) break;
          if (++it_ > (1 << 20)) break;
        }
      }
#pragma unroll
      for (int kc = 0; kc < 16; ++kc) {
        acc0 = __builtin_amdgcn_mfma_f32_16x16x32_bf16(fa[kc].b, w0[kc], acc0, 0, 0, 0);
        acc1 = __builtin_amdgcn_mfma_f32_16x16x32_bf16(fa[kc].b, w1[kc], acc1, 0, 0, 0);
      }
    }

    // ---- elementwise: pair lanes (l <-> l^8) hold {i,g} / {f,o} ----
    float hv[4];
#pragma unroll
    for (int r = 0; r < 4; ++r) {
      float a0 = acc0[r], a1 = acc1[r];
      float p0 = __shfl_xor(a0, 8);
      float p1 = __shfl_xor(a1, 8);
      float iv = owner ? a0 : p0;
      float fv = owner ? p0 : a0;
      float gv = owner ? a1 : p1;
      float ov = owner ? p1 : a1;
      iv = sigm(iv);
      fv = sigm(fv);
      gv = tanh_(gv);
      ov = sigm(ov);
      float cc = fv * creg[r] + iv * gv;
      creg[r] = cc;
      hv[r] = ov * tanh_(cc);
    }

    // ---- publish h_t: LDS micro-transpose -> ONE 4B store per lane ----
    {
#pragma unroll
      for (int r = 0; r < 4; ++r) {
        unsigned short hb = f2bf(hv[r]);
        unsigned int partner = (unsigned int)__shfl_xor((int)(unsigned int)hb, 1);
        unsigned int packed = ((unsigned int)hb & 0xffffu) | (partner << 16);
        if (pstore) xlds[(q * 4 + r) * 4 + (cmod >> 1)] = packed;
      }
      lgkm0();
      unsigned int v = xlds[lane];
      __hip_atomic_store((unsigned int*)(pubbase + (size_t)t * 32768), v,
                         __ATOMIC_RELAXED, __HIP_MEMORY_SCOPE_AGENT);
      asm volatile("" ::: "memory");
    }

    // ---- speculative round-1 issues for step t+1 (RT overlaps visibility,
    // out-stores, and input prefetch) ----
    if (t < TT) {
      if (layer == 0) {
        const char* hb2 = (const char*)myH +
                          ((size_t)t * 2 + mhalf) * 16384 + rdlane;
        GISSUE16(hb2, hb2 + 4096, hb2 + 8192, hb2 + 12288, fr);
      } else {
        const char* hb2 = (const char*)h1buf +
                          ((size_t)t * 2 + mhalf) * 16384 + rdlane;
        GISSUE16(hb2, hb2 + 4096, hb2 + 8192, hb2 + 12288, fr);
        const char* ha2 = (const char*)h0buf +
                          ((size_t)(t + 1) * 2 + mhalf) * 16384 + rdlane;
        GISSUE16(ha2, ha2 + 4096, ha2 + 8192, ha2 + 12288, fa);
      }
    }

    // ---- off-critical-path outputs (normal cached stores) ----
    if (layer) {
      float* op = out + (size_t)(t - 1) * BB * HH;
#pragma unroll
      for (int r = 0; r < 4; ++r) {
        int batch = mbase + q * 4 + r;
        if (owner) op[(size_t)batch * HH + hc0 + cmod] = hv[r];
      }
    }
    if (t == TT) {
      float* hn = out + (size_t)TT * BB * HH + (size_t)layer * BB * HH;
      float* cn = out + (size_t)TT * BB * HH + (size_t)2 * BB * HH + (size_t)layer * BB * HH;
#pragma unroll
      for (int r = 0; r < 4; ++r) {
        int batch = mbase + q * 4 + r;
        if (owner) {
          hn[(size_t)batch * HH + hc0 + cmod] = hv[r];
          cn[(size_t)batch * HH + hc0 + cmod] = creg[r];
        }
      }
    }

    // ---- prefetch next step's input projection operand (L0) ----
    if (use_xa && t < TT) {
      const unsigned short* ip = xbf + (size_t)t * BB * HH + laneoff;
#pragma unroll
      for (int kc = 0; kc < 16; ++kc)
        xa[kc] = *(const bf16x8*)(const void*)(ip + kc * 32);
    }
  }
}

extern "C" void kernel_launch(void* const* d_in, const int* in_sizes, int n_in,
                              void* d_out, int out_size, void* d_ws, size_t ws_size,
                              hipStream_t stream) {
  (void)in_sizes; (void)n_in; (void)out_size;
  const float* x = (const float*)d_in[0];
  const float* wih0 = (const float*)d_in[1];
  const float* whh0 = (const float*)d_in[2];
  const float* bih0 = (const float*)d_in[3];
  const float* bhh0 = (const float*)d_in[4];
  const float* wih1 = (const float*)d_in[5];
  const float* whh1 = (const float*)d_in[6];
  const float* bih1 = (const float*)d_in[7];
  const float* bhh1 = (const float*)d_in[8];
  const float* h0in = (const float*)d_in[9];
  const float* c0in = (const float*)d_in[10];
  float* out = (float*)d_out;
  char* ws = (char*)d_ws;

  const size_t hbuf_bytes = (size_t)(TT + 1) * 2 * 64 * 256;  // 33,587,200
  const size_t xbf_bytes = (size_t)TT * BB * HH * 2;          // 33,554,432

  unsigned short* h0b = (unsigned short*)ws;
  unsigned short* h1b = (unsigned short*)(ws + hbuf_bytes);
  size_t off = 2 * hbuf_bytes;
  bool use_xbf = ws_size >= off + xbf_bytes;
  unsigned short* xbf = use_xbf ? (unsigned short*)(ws + off) : nullptr;

  // Re-poison h buffers each launch (sentinel = 0xFFFF bf16 NaN pattern).
  hfill<<<dim3(4100), dim3(256), 0, stream>>>(
      (unsigned long long*)h0b, (unsigned long long*)h1b);
  if (use_xbf) xcvt<<<dim3(8192), dim3(256), 0, stream>>>(x, xbf);
  lstm_persistent<<<dim3(256), dim3(64), 0, stream>>>(
      x, wih0, whh0, bih0, bhh0, wih1, whh1, bih1, bhh1, h0in, c0in,
      out, xbf, h0b, h1b);
}

// Round 7
// 5361.345 us; speedup vs baseline: 1.9360x; 1.9360x over previous
//
#include <hip/hip_runtime.h>

#define TT 1024
#define BB 32
#define HH 512

typedef __attribute__((ext_vector_type(8))) __bf16 bf16x8;
typedef __attribute__((ext_vector_type(8))) short short8;
typedef __attribute__((ext_vector_type(4))) float f32x4;

union frag_u {
  short8 s;
  bf16x8 b;
  f32x4 f;
  unsigned long long q[2];
  unsigned int d[4];
};

__device__ __forceinline__ unsigned short f2bf(float f) {
  unsigned int u = __float_as_uint(f);
  u += 0x7FFFu + ((u >> 16) & 1u);
  return (unsigned short)(u >> 16);
}

__device__ __forceinline__ bf16x8 cvt8(const float* p) {
  frag_u u;
#pragma unroll
  for (int j = 0; j < 8; ++j) u.s[j] = (short)f2bf(p[j]);
  return u.b;
}

__device__ __forceinline__ float sigm(float x) {
  return __builtin_amdgcn_rcpf(1.0f + __expf(-x));
}
__device__ __forceinline__ float tanh_(float x) {
  return 1.0f - 2.0f * __builtin_amdgcn_rcpf(1.0f + __expf(2.0f * x));
}

__device__ __forceinline__ void lgkm0() {
  asm volatile("s_waitcnt lgkmcnt(0)" ::: "memory");
}

// Issue 16 coherence-point (sc0 sc1) 16B loads of one h fragment in the
// slice-blocked layout. fr[kc] = MFMA A-operand for K-block kc directly.
// NO WAIT inside: pair with POLLWAIT.
#define GISSUE16(A0, A1, A2, A3, FR)                                        \
  asm volatile(                                                             \
      "global_load_dwordx4 %0, %16, off sc0 sc1\n\t"                        \
      "global_load_dwordx4 %1, %16, off offset:1024 sc0 sc1\n\t"            \
      "global_load_dwordx4 %2, %16, off offset:2048 sc0 sc1\n\t"            \
      "global_load_dwordx4 %3, %16, off offset:3072 sc0 sc1\n\t"            \
      "global_load_dwordx4 %4, %17, off sc0 sc1\n\t"                        \
      "global_load_dwordx4 %5, %17, off offset:1024 sc0 sc1\n\t"            \
      "global_load_dwordx4 %6, %17, off offset:2048 sc0 sc1\n\t"            \
      "global_load_dwordx4 %7, %17, off offset:3072 sc0 sc1\n\t"            \
      "global_load_dwordx4 %8, %18, off sc0 sc1\n\t"                        \
      "global_load_dwordx4 %9, %18, off offset:1024 sc0 sc1\n\t"            \
      "global_load_dwordx4 %10, %18, off offset:2048 sc0 sc1\n\t"           \
      "global_load_dwordx4 %11, %18, off offset:3072 sc0 sc1\n\t"           \
      "global_load_dwordx4 %12, %19, off sc0 sc1\n\t"                       \
      "global_load_dwordx4 %13, %19, off offset:1024 sc0 sc1\n\t"           \
      "global_load_dwordx4 %14, %19, off offset:2048 sc0 sc1\n\t"           \
      "global_load_dwordx4 %15, %19, off offset:3072 sc0 sc1"               \
      : "=&v"((FR)[0].f), "=&v"((FR)[1].f), "=&v"((FR)[2].f),               \
        "=&v"((FR)[3].f), "=&v"((FR)[4].f), "=&v"((FR)[5].f),               \
        "=&v"((FR)[6].f), "=&v"((FR)[7].f), "=&v"((FR)[8].f),               \
        "=&v"((FR)[9].f), "=&v"((FR)[10].f), "=&v"((FR)[11].f),             \
        "=&v"((FR)[12].f), "=&v"((FR)[13].f), "=&v"((FR)[14].f),            \
        "=&v"((FR)[15].f)                                                   \
      : "v"((A0)), "v"((A1)), "v"((A2)), "v"((A3))                          \
      : "memory")

// Single-fragment reissue (adaptive rounds): only stale fragments re-fetch.
#define REISSUE(FRK, BASE, OFFSTR)                                          \
  asm volatile("global_load_dwordx4 %0, %1, off offset:" OFFSTR " sc0 sc1"  \
               : "=v"((FRK).f)                                              \
               : "v"((BASE))                                                \
               : "memory")

#define POLLWAIT                                       \
  do {                                                 \
    asm volatile("s_waitcnt vmcnt(0)" ::: "memory");   \
    __builtin_amdgcn_sched_barrier(0);                 \
  } while (0)

__device__ __forceinline__ unsigned int fbad1(const frag_u& f) {
  unsigned int b = 0u;
#pragma unroll
  for (int d = 0; d < 4; ++d) b |= (f.d[d] == 0xFFFFFFFFu) ? 1u : 0u;
  return b;
}

// Adaptive poll: round 1 loads the full 16-fragment slice (the poll IS the
// data load -- zero extra serialized legs); later rounds reissue ONLY the
// fragments still containing sentinel dwords. Each fragment covers 4 complete
// producer slices (16 lanes x 16B = 256B/slice), so per-fragment validity is
// exact. Steady state: 16KB round 1, then ~1-4KB -- cuts the MALL poll-storm
// ~4-8x without adding legs (R2's flag mistake) or registers (R6's spill).
#define ADPOLL(FR, HB)                                                      \
  do {                                                                      \
    const char* b0_ = (HB);                                                 \
    const char* b1_ = (HB) + 4096;                                          \
    const char* b2_ = (HB) + 8192;                                          \
    const char* b3_ = (HB) + 12288;                                         \
    GISSUE16(b0_, b1_, b2_, b3_, FR);                                       \
    int it_ = 0;                                                            \
    for (;;) {                                                              \
      POLLWAIT;                                                             \
      unsigned int m_ = 0u;                                                 \
      unsigned int bk_[16];                                                 \
      _Pragma("unroll")                                                     \
      for (int k_ = 0; k_ < 16; ++k_) {                                     \
        bk_[k_] = fbad1((FR)[k_]);                                          \
        m_ |= bk_[k_];                                                      \
      }                                                                     \
      if (__all(m_ == 0u)) break;                                           \
      if (++it_ > (1 << 20)) break;                                         \
      if (__any(bk_[0] != 0u)) REISSUE((FR)[0], b0_, "0");                  \
      if (__any(bk_[1] != 0u)) REISSUE((FR)[1], b0_, "1024");               \
      if (__any(bk_[2] != 0u)) REISSUE((FR)[2], b0_, "2048");               \
      if (__any(bk_[3] != 0u)) REISSUE((FR)[3], b0_, "3072");               \
      if (__any(bk_[4] != 0u)) REISSUE((FR)[4], b1_, "0");                  \
      if (__any(bk_[5] != 0u)) REISSUE((FR)[5], b1_, "1024");               \
      if (__any(bk_[6] != 0u)) REISSUE((FR)[6], b1_, "2048");               \
      if (__any(bk_[7] != 0u)) REISSUE((FR)[7], b1_, "3072");               \
      if (__any(bk_[8] != 0u)) REISSUE((FR)[8], b2_, "0");                  \
      if (__any(bk_[9] != 0u)) REISSUE((FR)[9], b2_, "1024");               \
      if (__any(bk_[10] != 0u)) REISSUE((FR)[10], b2_, "2048");             \
      if (__any(bk_[11] != 0u)) REISSUE((FR)[11], b2_, "3072");             \
      if (__any(bk_[12] != 0u)) REISSUE((FR)[12], b3_, "0");                \
      if (__any(bk_[13] != 0u)) REISSUE((FR)[13], b3_, "1024");             \
      if (__any(bk_[14] != 0u)) REISSUE((FR)[14], b3_, "2048");             \
      if (__any(bk_[15] != 0u)) REISSUE((FR)[15], b3_, "3072");             \
    }                                                                       \
  } while (0)

__global__ void xcvt(const float* __restrict__ x, unsigned short* __restrict__ xbf) {
  size_t i = (size_t)blockIdx.x * blockDim.x + threadIdx.x;  // 8192*256 = n/8 exact
  const f32x4* p = (const f32x4*)x + 2 * i;
  f32x4 a = p[0], b = p[1];
  short8 o;
  o[0] = (short)f2bf(a[0]); o[1] = (short)f2bf(a[1]);
  o[2] = (short)f2bf(a[2]); o[3] = (short)f2bf(a[3]);
  o[4] = (short)f2bf(b[0]); o[5] = (short)f2bf(b[1]);
  o[6] = (short)f2bf(b[2]); o[7] = (short)f2bf(b[3]);
  *((short8*)xbf + i) = o;
}

// Poison both h buffers with the sentinel pattern via agent-scope stores.
// Per buffer: (TT+1)*32KB = 4,198,400 qwords = 4100 blocks * 1024.
__global__ void hfill(unsigned long long* __restrict__ a,
                      unsigned long long* __restrict__ b) {
  size_t base = (size_t)blockIdx.x * 1024 + threadIdx.x;
#pragma unroll
  for (int k = 0; k < 4; ++k) {
    size_t i = base + (size_t)k * 256;
    __hip_atomic_store(a + i, ~0ull, __ATOMIC_RELAXED, __HIP_MEMORY_SCOPE_AGENT);
    __hip_atomic_store(b + i, ~0ull, __ATOMIC_RELAXED, __HIP_MEMORY_SCOPE_AGENT);
  }
}

// h buffers: slice-blocked layout [t][mhalf][slice(64)][row(16)][col(8)] bf16.
// Publish = one 4B store/lane (4 full lines/wave, no partial-line RMW).
// Consume = 16 x dwordx4, each lane-load IS an MFMA A-fragment.
__global__ __launch_bounds__(64, 1) void lstm_persistent(
    const float* __restrict__ x,
    const float* __restrict__ wih0, const float* __restrict__ whh0,
    const float* __restrict__ bih0, const float* __restrict__ bhh0,
    const float* __restrict__ wih1, const float* __restrict__ whh1,
    const float* __restrict__ bih1, const float* __restrict__ bhh1,
    const float* __restrict__ h0in, const float* __restrict__ c0in,
    float* __restrict__ out,
    const unsigned short* __restrict__ xbf,  // may be null -> read x fp32 directly
    unsigned short* __restrict__ h0buf,      // slice-blocked, sentinel-poisoned
    unsigned short* __restrict__ h1buf)
{
  __shared__ unsigned int xlds[64];          // 256B transpose scratch (1 wave/block)

  const int lane = threadIdx.x;            // 0..63
  const int bid = blockIdx.x;              // 0..255
  const int layer = bid >> 7;
  const int sub = bid & 127;
  const int mhalf = sub & 1;               // batch half
  const int slice = sub >> 1;              // 0..63 -> 8 h-cols each
  const int hc0 = slice << 3;
  const int q = lane >> 4;                 // MFMA quad
  const int c16 = lane & 15;               // MFMA n / m index
  const int cmod = lane & 7;
  const bool owner = (c16 < 8);
  const bool pstore = owner && !(c16 & 1); // packed-pair publisher lanes
  const int mbase = mhalf << 4;

  const float* wih = layer ? wih1 : wih0;
  const float* whh = layer ? whh1 : whh0;
  const float* bih = layer ? bih1 : bih0;
  const float* bhh = layer ? bhh1 : bhh0;

  // gate-column map: acc0 -> {i, f}, acc1 -> {g, o} for h-cols hc0..hc0+7
  const int colN0 = owner ? (hc0 + c16) : (512 + hc0 + c16 - 8);
  const int colN1 = owner ? (1024 + hc0 + c16) : (1536 + hc0 + c16 - 8);

  // ---- persistent weight fragments: [W_ih | W_hh] bf16, 256 VGPRs ----
  bf16x8 w0[32], w1[32];
#pragma unroll
  for (int kc = 0; kc < 32; ++kc) {
    const float* s0;
    const float* s1;
    if (kc < 16) {
      s0 = wih + (size_t)colN0 * HH + kc * 32 + q * 8;
      s1 = wih + (size_t)colN1 * HH + kc * 32 + q * 8;
    } else {
      s0 = whh + (size_t)colN0 * HH + (kc - 16) * 32 + q * 8;
      s1 = whh + (size_t)colN1 * HH + (kc - 16) * 32 + q * 8;
    }
    w0[kc] = cvt8(s0);
    w1[kc] = cvt8(s1);
  }
  const float bias0 = bih[colN0] + bhh[colN0];
  const float bias1 = bih[colN1] + bhh[colN1];

  // ---- initial cell state (pair lanes keep duplicates) ----
  float creg[4];
#pragma unroll
  for (int r = 0; r < 4; ++r) {
    int batch = mbase + q * 4 + r;
    creg[r] = c0in[(size_t)layer * BB * HH + (size_t)batch * HH + hc0 + cmod];
  }

  unsigned short* myH = layer ? h1buf : h0buf;
  char* pubbase = (char*)myH + (size_t)mhalf * 16384 + (size_t)slice * 256 +
                  (size_t)lane * 4;

  // ---- publish h_0 slice via LDS transpose + one wide store ----
  {
    float hv0[4];
#pragma unroll
    for (int r = 0; r < 4; ++r) {
      int batch = mbase + q * 4 + r;
      hv0[r] = h0in[(size_t)layer * BB * HH + (size_t)batch * HH + hc0 + cmod];
    }
#pragma unroll
    for (int r = 0; r < 4; ++r) {
      unsigned short hb = f2bf(hv0[r]);
      unsigned int partner = (unsigned int)__shfl_xor((int)(unsigned int)hb, 1);
      unsigned int packed = ((unsigned int)hb & 0xffffu) | (partner << 16);
      if (pstore) xlds[(q * 4 + r) * 4 + (cmod >> 1)] = packed;
    }
    lgkm0();
    unsigned int v = xlds[lane];
    __hip_atomic_store((unsigned int*)pubbase, v, __ATOMIC_RELAXED,
                       __HIP_MEMORY_SCOPE_AGENT);
    asm volatile("" ::: "memory");
  }

  const size_t laneoff = (size_t)(mbase + c16) * HH + q * 8;  // shorts (x rows)
  const size_t rdlane = (size_t)q * 256 + (size_t)c16 * 16;   // bytes in h layout

  for (int t = 1; t <= TT; ++t) {
    f32x4 acc0 = {bias0, bias0, bias0, bias0};
    f32x4 acc1 = {bias1, bias1, bias1, bias1};

    if (layer == 0) {
      // ---- input projection (xbf, cached loads), off critical path ----
      if (xbf != nullptr) {
        const unsigned short* ip = xbf + (size_t)(t - 1) * BB * HH + laneoff;
#pragma unroll
        for (int kc = 0; kc < 16; ++kc) {
          bf16x8 a = *(const bf16x8*)(const void*)(ip + kc * 32);
          acc0 = __builtin_amdgcn_mfma_f32_16x16x32_bf16(a, w0[kc], acc0, 0, 0, 0);
          acc1 = __builtin_amdgcn_mfma_f32_16x16x32_bf16(a, w1[kc], acc1, 0, 0, 0);
        }
      } else {
        const float* ip = x + (size_t)(t - 1) * BB * HH + laneoff;
#pragma unroll
        for (int kc = 0; kc < 16; ++kc) {
          bf16x8 a = cvt8(ip + kc * 32);
          acc0 = __builtin_amdgcn_mfma_f32_16x16x32_bf16(a, w0[kc], acc0, 0, 0, 0);
          acc1 = __builtin_amdgcn_mfma_f32_16x16x32_bf16(a, w1[kc], acc1, 0, 0, 0);
        }
      }

      // ---- adaptive poll of own h[t-1]: the poll IS the fragment load ----
      frag_u fr[16];
      {
        const char* hb = (const char*)myH +
                         ((size_t)(t - 1) * 2 + mhalf) * 16384 + rdlane;
        ADPOLL(fr, hb);
      }
#pragma unroll
      for (int kc = 0; kc < 16; ++kc) {
        acc0 = __builtin_amdgcn_mfma_f32_16x16x32_bf16(fr[kc].b, w0[16 + kc], acc0, 0, 0, 0);
        acc1 = __builtin_amdgcn_mfma_f32_16x16x32_bf16(fr[kc].b, w1[16 + kc], acc1, 0, 0, 0);
      }
    } else {
      // ---- layer 1: own h1[t-1] lands earlier than h0[t]; poll it first ----
      {
        frag_u fb[16];
        const char* hb = (const char*)h1buf +
                         ((size_t)(t - 1) * 2 + mhalf) * 16384 + rdlane;
        ADPOLL(fb, hb);
#pragma unroll
        for (int kc = 0; kc < 16; ++kc) {
          acc0 = __builtin_amdgcn_mfma_f32_16x16x32_bf16(fb[kc].b, w0[16 + kc], acc0, 0, 0, 0);
          acc1 = __builtin_amdgcn_mfma_f32_16x16x32_bf16(fb[kc].b, w1[16 + kc], acc1, 0, 0, 0);
        }
      }
      {
        frag_u fa[16];
        const char* ha = (const char*)h0buf +
                         ((size_t)t * 2 + mhalf) * 16384 + rdlane;
        ADPOLL(fa, ha);
#pragma unroll
        for (int kc = 0; kc < 16; ++kc) {
          acc0 = __builtin_amdgcn_mfma_f32_16x16x32_bf16(fa[kc].b, w0[kc], acc0, 0, 0, 0);
          acc1 = __builtin_amdgcn_mfma_f32_16x16x32_bf16(fa[kc].b, w1[kc], acc1, 0, 0, 0);
        }
      }
    }

    // ---- elementwise: pair lanes (l <-> l^8) hold {i,g} / {f,o} ----
    float hv[4];
#pragma unroll
    for (int r = 0; r < 4; ++r) {
      float a0 = acc0[r], a1 = acc1[r];
      float p0 = __shfl_xor(a0, 8);
      float p1 = __shfl_xor(a1, 8);
      float iv = owner ? a0 : p0;
      float fv = owner ? p0 : a0;
      float gv = owner ? a1 : p1;
      float ov = owner ? p1 : a1;
      iv = sigm(iv);
      fv = sigm(fv);
      gv = tanh_(gv);
      ov = sigm(ov);
      float cc = fv * creg[r] + iv * gv;
      creg[r] = cc;
      hv[r] = ov * tanh_(cc);
    }

    // ---- publish h_t: LDS micro-transpose -> ONE 4B store per lane
    // (256B contiguous per wave = 4 full lines, no partial-line RMW) ----
    {
#pragma unroll
      for (int r = 0; r < 4; ++r) {
        unsigned short hb = f2bf(hv[r]);
        unsigned int partner = (unsigned int)__shfl_xor((int)(unsigned int)hb, 1);
        unsigned int packed = ((unsigned int)hb & 0xffffu) | (partner << 16);
        if (pstore) xlds[(q * 4 + r) * 4 + (cmod >> 1)] = packed;
      }
      lgkm0();
      unsigned int v = xlds[lane];
      __hip_atomic_store((unsigned int*)(pubbase + (size_t)t * 32768), v,
                         __ATOMIC_RELAXED, __HIP_MEMORY_SCOPE_AGENT);
      asm volatile("" ::: "memory");
    }

    // ---- off-critical-path outputs (normal cached stores) ----
    if (layer) {
      float* op = out + (size_t)(t - 1) * BB * HH;
#pragma unroll
      for (int r = 0; r < 4; ++r) {
        int batch = mbase + q * 4 + r;
        if (owner) op[(size_t)batch * HH + hc0 + cmod] = hv[r];
      }
    }
    if (t == TT) {
      float* hn = out + (size_t)TT * BB * HH + (size_t)layer * BB * HH;
      float* cn = out + (size_t)TT * BB * HH + (size_t)2 * BB * HH + (size_t)layer * BB * HH;
#pragma unroll
      for (int r = 0; r < 4; ++r) {
        int batch = mbase + q * 4 + r;
        if (owner) {
          hn[(size_t)batch * HH + hc0 + cmod] = hv[r];
          cn[(size_t)batch * HH + hc0 + cmod] = creg[r];
        }
      }
    }
  }
}

extern "C" void kernel_launch(void* const* d_in, const int* in_sizes, int n_in,
                              void* d_out, int out_size, void* d_ws, size_t ws_size,
                              hipStream_t stream) {
  (void)in_sizes; (void)n_in; (void)out_size;
  const float* x = (const float*)d_in[0];
  const float* wih0 = (const float*)d_in[1];
  const float* whh0 = (const float*)d_in[2];
  const float* bih0 = (const float*)d_in[3];
  const float* bhh0 = (const float*)d_in[4];
  const float* wih1 = (const float*)d_in[5];
  const float* whh1 = (const float*)d_in[6];
  const float* bih1 = (const float*)d_in[7];
  const float* bhh1 = (const float*)d_in[8];
  const float* h0in = (const float*)d_in[9];
  const float* c0in = (const float*)d_in[10];
  float* out = (float*)d_out;
  char* ws = (char*)d_ws;

  const size_t hbuf_bytes = (size_t)(TT + 1) * 2 * 64 * 256;  // 33,587,200
  const size_t xbf_bytes = (size_t)TT * BB * HH * 2;          // 33,554,432

  unsigned short* h0b = (unsigned short*)ws;
  unsigned short* h1b = (unsigned short*)(ws + hbuf_bytes);
  size_t off = 2 * hbuf_bytes;
  bool use_xbf = ws_size >= off + xbf_bytes;
  unsigned short* xbf = use_xbf ? (unsigned short*)(ws + off) : nullptr;

  // Re-poison h buffers each launch (sentinel = 0xFFFF bf16 NaN pattern).
  hfill<<<dim3(4100), dim3(256), 0, stream>>>(
      (unsigned long long*)h0b, (unsigned long long*)h1b);
  if (use_xbf) xcvt<<<dim3(8192), dim3(256), 0, stream>>>(x, xbf);
  lstm_persistent<<<dim3(256), dim3(64), 0, stream>>>(
      x, wih0, whh0, bih0, bhh0, wih1, whh1, bih1, bhh1, h0in, c0in,
      out, xbf, h0b, h1b);
}